// Round 5
// baseline (250.415 us; speedup 1.0000x reference)
//
#include <hip/hip_runtime.h>
#include <hip/hip_bf16.h>
#include <math.h>

#define D_DIM 1024
#define NROWS 32768      // 4*16*512
#define NE_ROWS 1024     // 4*16*16 unique engram rows
#define A1_ROWS 1536     // engram rows + 512 pos rows
#define NT2 16           // GEMM2 K-tiles of 64

typedef __attribute__((ext_vector_type(8))) short bf16x8;
typedef __attribute__((ext_vector_type(4))) float f32x4;

static __device__ __forceinline__ ushort f2bf(float f) {
  union { float f; unsigned u; } un; un.f = f;
  unsigned u = un.u;
  unsigned r = u + 0x7fffu + ((u >> 16) & 1u);
  return (ushort)(r >> 16);
}
static __device__ __forceinline__ float bf2f(ushort h) {
  union { unsigned u; float f; } un; un.u = ((unsigned)h) << 16;
  return un.f;
}
// tanh-form GELU (max |err| vs exact erf-GELU ~3e-3; output impact ~2e-3)
static __device__ __forceinline__ float gelu_t(float x) {
  float x3 = x * x * x;
  float y = 0.7978845608f * x + 0.0356774081f * x3;
  float ay = fabsf(y);
  float t = __expf(-2.0f * ay);
  float th = __fdividef(1.0f - t, 1.0f + t);
  th = copysignf(th, y);
  return 0.5f * x * (1.0f + th);
}
static __device__ __forceinline__ float gelu_exact(float v) {
  return 0.5f * v * (1.0f + erff(v * 0.70710678118654752f));
}

// ---- fused cast fp32 -> bf16 of w1|w2|eng|pos into contiguous ws region ----
__global__ void cast_all_kernel(const float* __restrict__ w1, const float* __restrict__ w2,
                                const float* __restrict__ eng, const float* __restrict__ pos,
                                ushort* __restrict__ dst) {
  int i = blockIdx.x * blockDim.x + threadIdx.x;   // float4 units, 0..917503
  float4 v;
  if (i < 262144) v = ((const float4*)w1)[i];
  else if (i < 524288) v = ((const float4*)w2)[i - 262144];
  else if (i < 786432) v = ((const float4*)eng)[i - 524288];
  else v = ((const float4*)pos)[i - 786432];
  ushort4 o;
  o.x = f2bf(v.x); o.y = f2bf(v.y); o.z = f2bf(v.z); o.w = f2bf(v.w);
  ((ushort4*)dst)[i] = o;
}

// ---- 128x128 bf16 MFMA GEMM + optional row-ranged bias (for b1 folding) ----
__global__ __launch_bounds__(256) void gemm_bt(const ushort* __restrict__ A,
                                               const ushort* __restrict__ B,
                                               float* __restrict__ C,
                                               int M, int N, int K,
                                               const float* __restrict__ bias,
                                               int biasRow0) {
  __shared__ ushort sA[128 * 64];
  __shared__ ushort sB[128 * 64];

  int nwg = gridDim.x;
  int bid = blockIdx.x;
  if ((nwg & 7) == 0) {
    int cpx = nwg >> 3;
    bid = (bid & 7) * cpx + (bid >> 3);
  }
  int ntn = N >> 7;
  int mt = bid / ntn, nt = bid % ntn;
  int brow = mt << 7, bcol = nt << 7;

  int tid = threadIdx.x;
  int wv = tid >> 6, lane = tid & 63;
  int wm = (wv >> 1) << 6, wn = (wv & 1) << 6;
  int lr = lane & 15, lk = lane >> 4;
  int srow = lane >> 3;
  int scolsw = (((lane & 7) ^ ((lane >> 3) & 7)) << 3);

  f32x4 acc[4][4];
#pragma unroll
  for (int m = 0; m < 4; ++m)
#pragma unroll
    for (int n = 0; n < 4; ++n) acc[m][n] = (f32x4){0.f, 0.f, 0.f, 0.f};

  for (int k0 = 0; k0 < K; k0 += 64) {
    __syncthreads();
#pragma unroll
    for (int j = 0; j < 4; ++j) {
      int c = (wv << 2) + j;
      int row = (c << 3) + srow;
      const ushort* gA = A + (brow + row) * K + k0 + scolsw;
      const ushort* gB = B + (bcol + row) * K + k0 + scolsw;
      __builtin_amdgcn_global_load_lds(
          (const __attribute__((address_space(1))) unsigned int*)gA,
          (__attribute__((address_space(3))) unsigned int*)&sA[c << 9], 16, 0, 0);
      __builtin_amdgcn_global_load_lds(
          (const __attribute__((address_space(1))) unsigned int*)gB,
          (__attribute__((address_space(3))) unsigned int*)&sB[c << 9], 16, 0, 0);
    }
    __syncthreads();
#pragma unroll
    for (int kk = 0; kk < 2; ++kk) {
      int rdoff = (((kk << 2) | lk) ^ (lr & 7)) << 3;
      bf16x8 af[4], bfr[4];
#pragma unroll
      for (int m = 0; m < 4; ++m)
        af[m] = *(const bf16x8*)&sA[(wm + (m << 4) + lr) * 64 + rdoff];
#pragma unroll
      for (int n = 0; n < 4; ++n)
        bfr[n] = *(const bf16x8*)&sB[(wn + (n << 4) + lr) * 64 + rdoff];
#pragma unroll
      for (int m = 0; m < 4; ++m)
#pragma unroll
        for (int n = 0; n < 4; ++n)
          acc[m][n] = __builtin_amdgcn_mfma_f32_16x16x32_bf16(af[m], bfr[n], acc[m][n], 0, 0, 0);
    }
  }

#pragma unroll
  for (int m = 0; m < 4; ++m)
#pragma unroll
    for (int n = 0; n < 4; ++n)
#pragma unroll
      for (int i = 0; i < 4; ++i) {
        int row = brow + wm + (m << 4) + (lk << 2) + i;
        int col = bcol + wn + (n << 4) + lr;
        float v = acc[m][n][i];
        if (row >= biasRow0) v += bias[col];
        C[(long)row * N + col] = v;
      }
}

// ---- GEMM2: 8-phase 256x256, A = gelu(xw1_e + xw1_p) built in-register ----
// Y(bf16) = gelu(...) @ W2^T, Y interleaved: ushort at Y + row*2048 + col.
// B via global_load_lds (counted vmcnt); A via f32 loads -> gelu -> ds_write.
// Swizzle: phys 16B-slot s at row r holds logical s^((r>>1)&3).
__global__ __launch_bounds__(512, 2) void gemm2_8ph(const float* __restrict__ xw1,
                                                    const ushort* __restrict__ B,
                                                    ushort* __restrict__ Y) {
  __shared__ ushort sA[2][2][8192];
  __shared__ ushort sB[2][2][8192];
  const int K = 1024;

  int bid = blockIdx.x;
  bid = (bid & 7) * 64 + (bid >> 3);          // 512 blocks, XCD swizzle
  int mt = bid >> 2, nt = bid & 3;            // 128 M-tiles x 4 N-tiles
  long brow = (long)mt << 8;
  int bcol = nt << 8;
  int w0 = (int)(brow & 511);
  int bn = (int)(brow >> 9);
  int er0 = bn * 16 + (w0 >> 5);

  int tid = threadIdx.x;
  int wv = tid >> 6, l = tid & 63;
  int wr = wv >> 2, wc = wv & 3;              // 2x4 wave grid; wave tile 128x64
  int lr = l & 15, lk = l >> 4;

  // B staging source (per-thread, pre-swizzled global k-slot)
  int sr = (wv << 4) + (l >> 2);              // region row for j=0 (0..127)
  int slog = ((l & 3) ^ ((l >> 3) & 3)) << 3;
  const ushort* bS = B + (size_t)(bcol + sr) * K + slog;

  // A staging: thread -> row ar, k-half kh (16 floats)
  int ar = tid >> 1;
  int kh = tid & 1;
  const float* aE = xw1 + ((size_t)(er0 + (ar >> 5)) << 10) + (kh << 4);
  const float* aP = xw1 + ((size_t)(NE_ROWS + w0 + ar) << 10) + (kh << 4);
  int swz = (ar >> 1) & 3;
  int wA0 = ar * 32 + ((((kh << 1) | 0) ^ swz) << 3);
  int wA1 = ar * 32 + ((((kh << 1) | 1) ^ swz) << 3);

  // fragment read offsets (swizzled)
  int rdswz = (lk ^ ((lr >> 1) & 3)) << 3;
  int aO = (((wr << 7) + lr) << 5) + rdswz;   // + m*512
  int bO = (((wc << 6) + lr) << 5) + rdswz;   // + n*512

  f32x4 acc[8][4];
#pragma unroll
  for (int m = 0; m < 8; ++m)
#pragma unroll
    for (int n = 0; n < 4; ++n) acc[m][n] = (f32x4){0.f, 0.f, 0.f, 0.f};

#define STGB(kt, kkh) do {                                                           \
    int p_ = (kt) & 1; int o_ = ((kt) << 6) + ((kkh) << 5);                          \
    __builtin_amdgcn_global_load_lds(                                                \
      (const __attribute__((address_space(1))) unsigned int*)(bS + o_),              \
      (__attribute__((address_space(3))) unsigned int*)&sB[p_][kkh][wv << 9], 16, 0, 0); \
    __builtin_amdgcn_global_load_lds(                                                \
      (const __attribute__((address_space(1))) unsigned int*)(bS + o_ + 131072),     \
      (__attribute__((address_space(3))) unsigned int*)&sB[p_][kkh][(wv << 9) + 4096], 16, 0, 0); \
  } while (0)

#define LOADA(eD, pD, kb) do {                                                       \
    _Pragma("unroll")                                                                \
    for (int j = 0; j < 4; ++j) {                                                    \
      eD[j] = *(const float4*)(aE + (kb) + (j << 2));                                \
      pD[j] = *(const float4*)(aP + (kb) + (j << 2));                                \
    }                                                                                \
    __builtin_amdgcn_sched_barrier(0);                                               \
  } while (0)

#define WRITEA(SS, eD, pD) do {                                                      \
    bf16x8 lo_, hi_;                                                                 \
    lo_[0]=(short)f2bf(gelu_t(eD[0].x+pD[0].x)); lo_[1]=(short)f2bf(gelu_t(eD[0].y+pD[0].y)); \
    lo_[2]=(short)f2bf(gelu_t(eD[0].z+pD[0].z)); lo_[3]=(short)f2bf(gelu_t(eD[0].w+pD[0].w)); \
    lo_[4]=(short)f2bf(gelu_t(eD[1].x+pD[1].x)); lo_[5]=(short)f2bf(gelu_t(eD[1].y+pD[1].y)); \
    lo_[6]=(short)f2bf(gelu_t(eD[1].z+pD[1].z)); lo_[7]=(short)f2bf(gelu_t(eD[1].w+pD[1].w)); \
    hi_[0]=(short)f2bf(gelu_t(eD[2].x+pD[2].x)); hi_[1]=(short)f2bf(gelu_t(eD[2].y+pD[2].y)); \
    hi_[2]=(short)f2bf(gelu_t(eD[2].z+pD[2].z)); hi_[3]=(short)f2bf(gelu_t(eD[2].w+pD[2].w)); \
    hi_[4]=(short)f2bf(gelu_t(eD[3].x+pD[3].x)); hi_[5]=(short)f2bf(gelu_t(eD[3].y+pD[3].y)); \
    hi_[6]=(short)f2bf(gelu_t(eD[3].z+pD[3].z)); hi_[7]=(short)f2bf(gelu_t(eD[3].w+pD[3].w)); \
    *(bf16x8*)&SS[wA0] = lo_;                                                        \
    *(bf16x8*)&SS[wA1] = hi_;                                                        \
  } while (0)

#define BAR asm volatile("s_barrier" ::: "memory")
#define MFMA16(MOFS, BF)                                                             \
    __builtin_amdgcn_s_setprio(1);                                                   \
    _Pragma("unroll")                                                                \
    for (int m = 0; m < 4; ++m)                                                      \
      _Pragma("unroll")                                                              \
      for (int n = 0; n < 4; ++n)                                                    \
        acc[m + MOFS][n] = __builtin_amdgcn_mfma_f32_16x16x32_bf16(af[m], BF[n], acc[m + MOFS][n], 0, 0, 0); \
    __builtin_amdgcn_s_setprio(0)

  float4 e0[4], p0[4], e1[4], p1[4];

  // ---- prologue: tile 0 ----
  LOADA(e0, p0, 0);          // tile0 kk0
  LOADA(e1, p1, 32);         // tile0 kk1 (written at t=0 ph2)
  WRITEA(sA[0][0], e0, p0);
  STGB(0, 0); STGB(0, 1);
  __syncthreads();           // full drain + barrier

  for (int t = 0; t < NT2; ++t) {
    int p = t & 1, q = p ^ 1;
    bf16x8 af[4], bf[4];
    // ---- ph1: (mh0, kk0) ----
    if (t + 1 < NT2) LOADA(e0, p0, ((t + 1) << 6));
#pragma unroll
    for (int n = 0; n < 4; ++n) bf[n] = *(const bf16x8*)&sB[p][0][bO + (n << 9)];
#pragma unroll
    for (int m = 0; m < 4; ++m) af[m] = *(const bf16x8*)&sA[p][0][aO + (m << 9)];
    BAR;
    MFMA16(0, bf);
    BAR;
    // ---- ph2: (mh1, kk0) ----
#pragma unroll
    for (int m = 0; m < 4; ++m) af[m] = *(const bf16x8*)&sA[p][0][aO + ((m + 4) << 9)];
    if (t + 1 < NT2) STGB(t + 1, 0);
    BAR;
    MFMA16(4, bf);
    WRITEA(sA[p][1], e1, p1);   // tile t kk1 (compiler waits its f32 loads)
    if (t == NT2 - 1) asm volatile("s_waitcnt vmcnt(0)" ::: "memory");
    else              asm volatile("s_waitcnt vmcnt(10)" ::: "memory"); // certify B(t,kk1)
    asm volatile("s_waitcnt lgkmcnt(0)" ::: "memory");
    BAR;
    // ---- ph3: (mh0, kk1) ----
    if (t + 1 < NT2) LOADA(e1, p1, ((t + 1) << 6) + 32);
#pragma unroll
    for (int n = 0; n < 4; ++n) bf[n] = *(const bf16x8*)&sB[p][1][bO + (n << 9)];
#pragma unroll
    for (int m = 0; m < 4; ++m) af[m] = *(const bf16x8*)&sA[p][1][aO + (m << 9)];
    BAR;
    MFMA16(0, bf);
    BAR;
    // ---- ph4: (mh1, kk1) ----
#pragma unroll
    for (int m = 0; m < 4; ++m) af[m] = *(const bf16x8*)&sA[p][1][aO + ((m + 4) << 9)];
    if (t + 1 < NT2) STGB(t + 1, 1);
    BAR;
    MFMA16(4, bf);
    if (t + 1 < NT2) {
      WRITEA(sA[q][0], e0, p0);  // tile t+1 kk0
      asm volatile("s_waitcnt vmcnt(10)" ::: "memory");  // certify B(t+1,kk0)
    }
    asm volatile("s_waitcnt lgkmcnt(0)" ::: "memory");
    BAR;
  }
#undef STGB
#undef LOADA
#undef WRITEA
#undef BAR
#undef MFMA16

  // epilogue: bf16 y into interleaved out rows (first 1024 ushorts of 4KB row)
#pragma unroll
  for (int m = 0; m < 8; ++m)
#pragma unroll
    for (int n = 0; n < 4; ++n) {
      int col = bcol + (wc << 6) + (n << 4) + lr;
#pragma unroll
      for (int i = 0; i < 4; ++i) {
        long row = brow + (wr << 7) + (m << 4) + (lk << 2) + i;
        Y[(row << 11) + col] = f2bf(acc[m][n][i]);
      }
    }
}

// ---- out = LayerNorm((eng+pos) + y + b2); y read bf16-interleaved from out ----
__global__ __launch_bounds__(256) void ln_kernel(const float* __restrict__ eng,
                                                 const float* __restrict__ pos,
                                                 const float* __restrict__ b2,
                                                 const float* __restrict__ gamma,
                                                 const float* __restrict__ beta,
                                                 float* __restrict__ out) {
  __shared__ float red[8];
  int r = blockIdx.x;
  int t = threadIdx.x;
  int bn = r >> 9, w = r & 511;
  int er = bn * 16 + (w >> 5);
  float4 xe = ((const float4*)(eng + er * D_DIM))[t];
  float4 xp = ((const float4*)(pos + w * D_DIM))[t];
  ushort4 yv = ((const ushort4*)((const ushort*)out + ((size_t)r << 11)))[t];
  float4 bb = ((const float4*)b2)[t];
  float v0 = xe.x + xp.x + bf2f(yv.x) + bb.x;
  float v1 = xe.y + xp.y + bf2f(yv.y) + bb.y;
  float v2 = xe.z + xp.z + bf2f(yv.z) + bb.z;
  float v3 = xe.w + xp.w + bf2f(yv.w) + bb.w;
  float s  = v0 + v1 + v2 + v3;
  float sq = v0 * v0 + v1 * v1 + v2 * v2 + v3 * v3;
  int lane = t & 63, wv = t >> 6;
#pragma unroll
  for (int off = 32; off > 0; off >>= 1) {
    s  += __shfl_down(s, off);
    sq += __shfl_down(sq, off);
  }
  if (lane == 0) { red[wv] = s; red[4 + wv] = sq; }
  __syncthreads();
  float S  = red[0] + red[1] + red[2] + red[3];
  float SQ = red[4] + red[5] + red[6] + red[7];
  float mu = S * (1.0f / 1024.0f);
  float var = SQ * (1.0f / 1024.0f) - mu * mu;
  float rs = rsqrtf(var + 1e-5f);
  float4 g = ((const float4*)gamma)[t];
  float4 bt = ((const float4*)beta)[t];
  float4 o;
  o.x = (v0 - mu) * rs * g.x + bt.x;
  o.y = (v1 - mu) * rs * g.y + bt.y;
  o.z = (v2 - mu) * rs * g.z + bt.z;
  o.w = (v3 - mu) * rs * g.w + bt.w;
  ((float4*)(out + ((size_t)r << 10)))[t] = o;
}

extern "C" void kernel_launch(void* const* d_in, const int* in_sizes, int n_in,
                              void* d_out, int out_size, void* d_ws, size_t ws_size,
                              hipStream_t stream) {
  const float* eng   = (const float*)d_in[0];
  const float* pos   = (const float*)d_in[1];
  const float* w1    = (const float*)d_in[2];
  const float* b1    = (const float*)d_in[3];
  const float* w2    = (const float*)d_in[4];
  const float* b2    = (const float*)d_in[5];
  const float* gamma = (const float*)d_in[6];
  const float* beta  = (const float*)d_in[7];
  float* out = (float*)d_out;

  char* ws = (char*)d_ws;
  ushort* w1b = (ushort*)(ws);                     // 2 MiB  (cast block start)
  ushort* w2b = (ushort*)(ws + (2u << 20));        // 2 MiB
  ushort* a1b = (ushort*)(ws + (4u << 20));        // 3 MiB: [eng;pos] bf16
  float*  xw1 = (float*)(ws + (7u << 20));         // 6 MiB: 1536x1024 f32

  // 1) fused casts to bf16 (w1|w2|eng|pos contiguous at ws base)
  cast_all_kernel<<<3584, 256, 0, stream>>>(w1, w2, eng, pos, w1b);

  // 2) GEMM1: xw1 = [engrams; pos] @ W1^T, +b1 folded into pos-rows (1024..1535)
  gemm_bt<<<(A1_ROWS / 128) * (D_DIM / 128), 256, 0, stream>>>(a1b, w1b, xw1,
                                                               A1_ROWS, D_DIM, D_DIM,
                                                               b1, NE_ROWS);

  // 3) GEMM2 (8-phase, gelu fused into A-staging): y(bf16) interleaved into d_out
  gemm2_8ph<<<512, 512, 0, stream>>>(xw1, w2b, (ushort*)out);

  // 4) LayerNorm epilogue (exact fp32 residual recompute)
  ln_kernel<<<NROWS, 256, 0, stream>>>(eng, pos, b2, gamma, beta, out);
}

// Round 6
// 178.914 us; speedup vs baseline: 1.3996x; 1.3996x over previous
//
#include <hip/hip_runtime.h>
#include <hip/hip_bf16.h>
#include <math.h>

#define D_DIM 1024
#define NROWS 32768      // 4*16*512
#define NE_ROWS 1024     // 4*16*16 unique engram rows
#define A1_ROWS 1536     // engram rows + 512 pos rows
#define NT2 16           // GEMM2 K-tiles of 64

typedef __attribute__((ext_vector_type(8))) short bf16x8;
typedef __attribute__((ext_vector_type(4))) float f32x4;

static __device__ __forceinline__ ushort f2bf(float f) {
  union { float f; unsigned u; } un; un.f = f;
  unsigned u = un.u;
  unsigned r = u + 0x7fffu + ((u >> 16) & 1u);
  return (ushort)(r >> 16);
}
static __device__ __forceinline__ float bf2f(ushort h) {
  union { unsigned u; float f; } un; un.u = ((unsigned)h) << 16;
  return un.f;
}
static __device__ __forceinline__ float gelu_exact(float v) {
  return 0.5f * v * (1.0f + erff(v * 0.70710678118654752f));
}

// ---- fused cast fp32 -> bf16 of w1|w2|eng|pos into contiguous ws region ----
__global__ void cast_all_kernel(const float* __restrict__ w1, const float* __restrict__ w2,
                                const float* __restrict__ eng, const float* __restrict__ pos,
                                ushort* __restrict__ dst) {
  int i = blockIdx.x * blockDim.x + threadIdx.x;   // float4 units, 0..917503
  float4 v;
  if (i < 262144) v = ((const float4*)w1)[i];
  else if (i < 524288) v = ((const float4*)w2)[i - 262144];
  else if (i < 786432) v = ((const float4*)eng)[i - 524288];
  else v = ((const float4*)pos)[i - 786432];
  ushort4 o;
  o.x = f2bf(v.x); o.y = f2bf(v.y); o.z = f2bf(v.z); o.w = f2bf(v.w);
  ((ushort4*)dst)[i] = o;
}

// ---- 128x128 bf16 MFMA GEMM + row-ranged bias (b1 folded into pos rows) ----
__global__ __launch_bounds__(256) void gemm_bt(const ushort* __restrict__ A,
                                               const ushort* __restrict__ B,
                                               float* __restrict__ C,
                                               int M, int N, int K,
                                               const float* __restrict__ bias,
                                               int biasRow0) {
  __shared__ ushort sA[128 * 64];
  __shared__ ushort sB[128 * 64];

  int nwg = gridDim.x;
  int bid = blockIdx.x;
  if ((nwg & 7) == 0) {
    int cpx = nwg >> 3;
    bid = (bid & 7) * cpx + (bid >> 3);
  }
  int ntn = N >> 7;
  int mt = bid / ntn, nt = bid % ntn;
  int brow = mt << 7, bcol = nt << 7;

  int tid = threadIdx.x;
  int wv = tid >> 6, lane = tid & 63;
  int wm = (wv >> 1) << 6, wn = (wv & 1) << 6;
  int lr = lane & 15, lk = lane >> 4;
  int srow = lane >> 3;
  int scolsw = (((lane & 7) ^ ((lane >> 3) & 7)) << 3);

  f32x4 acc[4][4];
#pragma unroll
  for (int m = 0; m < 4; ++m)
#pragma unroll
    for (int n = 0; n < 4; ++n) acc[m][n] = (f32x4){0.f, 0.f, 0.f, 0.f};

  for (int k0 = 0; k0 < K; k0 += 64) {
    __syncthreads();
#pragma unroll
    for (int j = 0; j < 4; ++j) {
      int c = (wv << 2) + j;
      int row = (c << 3) + srow;
      const ushort* gA = A + (brow + row) * K + k0 + scolsw;
      const ushort* gB = B + (bcol + row) * K + k0 + scolsw;
      __builtin_amdgcn_global_load_lds(
          (const __attribute__((address_space(1))) unsigned int*)gA,
          (__attribute__((address_space(3))) unsigned int*)&sA[c << 9], 16, 0, 0);
      __builtin_amdgcn_global_load_lds(
          (const __attribute__((address_space(1))) unsigned int*)gB,
          (__attribute__((address_space(3))) unsigned int*)&sB[c << 9], 16, 0, 0);
    }
    __syncthreads();
#pragma unroll
    for (int kk = 0; kk < 2; ++kk) {
      int rdoff = (((kk << 2) | lk) ^ (lr & 7)) << 3;
      bf16x8 af[4], bfr[4];
#pragma unroll
      for (int m = 0; m < 4; ++m)
        af[m] = *(const bf16x8*)&sA[(wm + (m << 4) + lr) * 64 + rdoff];
#pragma unroll
      for (int n = 0; n < 4; ++n)
        bfr[n] = *(const bf16x8*)&sB[(wn + (n << 4) + lr) * 64 + rdoff];
#pragma unroll
      for (int m = 0; m < 4; ++m)
#pragma unroll
        for (int n = 0; n < 4; ++n)
          acc[m][n] = __builtin_amdgcn_mfma_f32_16x16x32_bf16(af[m], bfr[n], acc[m][n], 0, 0, 0);
    }
  }

#pragma unroll
  for (int m = 0; m < 4; ++m)
#pragma unroll
    for (int n = 0; n < 4; ++n)
#pragma unroll
      for (int i = 0; i < 4; ++i) {
        int row = brow + wm + (m << 4) + (lk << 2) + i;
        int col = bcol + wn + (n << 4) + lr;
        float v = acc[m][n][i];
        if (row >= biasRow0) v += bias[col];
        C[(long)row * N + col] = v;
      }
}

// ---- h = gelu_exact(xw1_e[er] + xw1_p[w]) -> bf16 (b1 already in pos rows) ----
__global__ __launch_bounds__(256) void gelu_kernel(const float* __restrict__ xw1,
                                                   ushort* __restrict__ h) {
  int r = blockIdx.x;
  int t = threadIdx.x;
  int bn = r >> 9;
  int w = r & 511;
  int er = bn * 16 + (w >> 5);
  float4 e = ((const float4*)(xw1 + er * D_DIM))[t];
  float4 p = ((const float4*)(xw1 + (NE_ROWS + w) * D_DIM))[t];
  ushort4 o;
  o.x = f2bf(gelu_exact(e.x + p.x));
  o.y = f2bf(gelu_exact(e.y + p.y));
  o.z = f2bf(gelu_exact(e.z + p.z));
  o.w = f2bf(gelu_exact(e.w + p.w));
  ((ushort4*)(h + (long)r * D_DIM))[t] = o;
}

// ---- GEMM2: 128x128 tile, 4 waves, 2 blocks/CU, counted-vmcnt pipeline ----
// Y(bf16) = h @ W2^T, interleaved: ushort at Y + row*2048 + col.
// BK=64 in 2 kk-phases; LDS 64 KiB = [parity][kkh][128r x 32k] for A and B.
// Swizzle: phys 16B-slot s at row r holds logical s^((r>>1)&3).
__global__ __launch_bounds__(256, 2) void gemm2_128(const ushort* __restrict__ A,
                                                    const ushort* __restrict__ B,
                                                    ushort* __restrict__ Y) {
  __shared__ ushort sA[2][2][4096];
  __shared__ ushort sB[2][2][4096];
  const int K = 1024;

  // XCD map: all 8 N-tiles of an M-panel stay on one XCD (A L2-reuse)
  int bid = blockIdx.x;                // 2048 blocks
  int x = bid & 7, jj = bid >> 3;
  int mt = (x << 5) + (jj >> 3);       // 0..255
  int nt = jj & 7;                     // 0..7
  long brow = (long)mt << 7;
  int bcol = nt << 7;

  int tid = threadIdx.x;
  int wv = tid >> 6, l = tid & 63;
  int wr = wv >> 1, wc = wv & 1;       // 2x2 wave grid; wave tile 64x64
  int lr = l & 15, lk = l >> 4;

  // staging: instr j2: row = j2*64 + wv*16 + (l>>2); lane phys slot l&3,
  // pre-swizzled logical slot (l&3)^((l>>3)&3)  [= (row>>1)&3 for this map]
  int srow0 = (wv << 4) + (l >> 2);
  int slog = (((l & 3) ^ ((l >> 3) & 3)) << 3);
  const ushort* aS = A + (brow + srow0) * (long)K + slog;
  const ushort* bS = B + (size_t)(bcol + srow0) * K + slog;

  // fragment read offsets (swizzled)
  int rdswz = (lk ^ ((lr >> 1) & 3)) << 3;
  int aO = (((wr << 6) + lr) << 5) + rdswz;   // + m<<9
  int bO = (((wc << 6) + lr) << 5) + rdswz;   // + n<<9

  f32x4 acc[4][4];
#pragma unroll
  for (int m = 0; m < 4; ++m)
#pragma unroll
    for (int n = 0; n < 4; ++n) acc[m][n] = (f32x4){0.f, 0.f, 0.f, 0.f};

#define STG(kt, kkh) do {                                                            \
    int p_ = (kt) & 1; int ko_ = ((kt) << 6) + ((kkh) << 5);                         \
    _Pragma("unroll")                                                                \
    for (int j2 = 0; j2 < 2; ++j2) {                                                 \
      __builtin_amdgcn_global_load_lds(                                              \
        (const __attribute__((address_space(1))) unsigned int*)(aS + ko_ + (long)(j2 << 6) * K), \
        (__attribute__((address_space(3))) unsigned int*)&sA[p_][kkh][(j2 << 11) + (wv << 9)], 16, 0, 0); \
      __builtin_amdgcn_global_load_lds(                                              \
        (const __attribute__((address_space(1))) unsigned int*)(bS + ko_ + (long)(j2 << 6) * K), \
        (__attribute__((address_space(3))) unsigned int*)&sB[p_][kkh][(j2 << 11) + (wv << 9)], 16, 0, 0); \
    } } while (0)

#define BAR asm volatile("s_barrier" ::: "memory")

  // prologue: tile 0 both halves in flight; certify kk0 only
  STG(0, 0); STG(0, 1);
  asm volatile("s_waitcnt vmcnt(4)" ::: "memory");
  BAR;

  for (int t = 0; t < NT2; ++t) {
    int p = t & 1;
#pragma unroll
    for (int kk = 0; kk < 2; ++kk) {
      bf16x8 af[4], bf[4];
#pragma unroll
      for (int n = 0; n < 4; ++n) bf[n] = *(const bf16x8*)&sB[p][kk][bO + (n << 9)];
#pragma unroll
      for (int m = 0; m < 4; ++m) af[m] = *(const bf16x8*)&sA[p][kk][aO + (m << 9)];
      if (t + 1 < NT2) STG(t + 1, kk);
      BAR;
      __builtin_amdgcn_s_setprio(1);
#pragma unroll
      for (int m = 0; m < 4; ++m)
#pragma unroll
        for (int n = 0; n < 4; ++n)
          acc[m][n] = __builtin_amdgcn_mfma_f32_16x16x32_bf16(af[m], bf[n], acc[m][n], 0, 0, 0);
      __builtin_amdgcn_s_setprio(0);
      if (t + 1 < NT2) asm volatile("s_waitcnt vmcnt(4)" ::: "memory");
      else             asm volatile("s_waitcnt vmcnt(0)" ::: "memory");
      BAR;
    }
  }
#undef STG
#undef BAR

  // epilogue: bf16 y into interleaved out rows (first 1024 ushorts of 4KB row)
#pragma unroll
  for (int m = 0; m < 4; ++m)
#pragma unroll
    for (int n = 0; n < 4; ++n) {
      int col = bcol + (wc << 6) + (n << 4) + lr;
#pragma unroll
      for (int i = 0; i < 4; ++i) {
        long row = brow + (wr << 6) + (m << 4) + (lk << 2) + i;
        Y[(row << 11) + col] = f2bf(acc[m][n][i]);
      }
    }
}

// ---- out = LayerNorm((eng+pos) + y + b2); y read bf16-interleaved from out ----
__global__ __launch_bounds__(256) void ln_kernel(const float* __restrict__ eng,
                                                 const float* __restrict__ pos,
                                                 const float* __restrict__ b2,
                                                 const float* __restrict__ gamma,
                                                 const float* __restrict__ beta,
                                                 float* __restrict__ out) {
  __shared__ float red[8];
  int r = blockIdx.x;
  int t = threadIdx.x;
  int bn = r >> 9, w = r & 511;
  int er = bn * 16 + (w >> 5);
  float4 xe = ((const float4*)(eng + er * D_DIM))[t];
  float4 xp = ((const float4*)(pos + w * D_DIM))[t];
  ushort4 yv = ((const ushort4*)((const ushort*)out + ((size_t)r << 11)))[t];
  float4 bb = ((const float4*)b2)[t];
  float v0 = xe.x + xp.x + bf2f(yv.x) + bb.x;
  float v1 = xe.y + xp.y + bf2f(yv.y) + bb.y;
  float v2 = xe.z + xp.z + bf2f(yv.z) + bb.z;
  float v3 = xe.w + xp.w + bf2f(yv.w) + bb.w;
  float s  = v0 + v1 + v2 + v3;
  float sq = v0 * v0 + v1 * v1 + v2 * v2 + v3 * v3;
  int lane = t & 63, wv = t >> 6;
#pragma unroll
  for (int off = 32; off > 0; off >>= 1) {
    s  += __shfl_down(s, off);
    sq += __shfl_down(sq, off);
  }
  if (lane == 0) { red[wv] = s; red[4 + wv] = sq; }
  __syncthreads();
  float S  = red[0] + red[1] + red[2] + red[3];
  float SQ = red[4] + red[5] + red[6] + red[7];
  float mu = S * (1.0f / 1024.0f);
  float var = SQ * (1.0f / 1024.0f) - mu * mu;
  float rs = rsqrtf(var + 1e-5f);
  float4 g = ((const float4*)gamma)[t];
  float4 bt = ((const float4*)beta)[t];
  float4 o;
  o.x = (v0 - mu) * rs * g.x + bt.x;
  o.y = (v1 - mu) * rs * g.y + bt.y;
  o.z = (v2 - mu) * rs * g.z + bt.z;
  o.w = (v3 - mu) * rs * g.w + bt.w;
  ((float4*)(out + ((size_t)r << 10)))[t] = o;
}

extern "C" void kernel_launch(void* const* d_in, const int* in_sizes, int n_in,
                              void* d_out, int out_size, void* d_ws, size_t ws_size,
                              hipStream_t stream) {
  const float* eng   = (const float*)d_in[0];
  const float* pos   = (const float*)d_in[1];
  const float* w1    = (const float*)d_in[2];
  const float* b1    = (const float*)d_in[3];
  const float* w2    = (const float*)d_in[4];
  const float* b2    = (const float*)d_in[5];
  const float* gamma = (const float*)d_in[6];
  const float* beta  = (const float*)d_in[7];
  float* out = (float*)d_out;

  char* ws = (char*)d_ws;
  ushort* w1b = (ushort*)(ws);                     // 2 MiB  (cast block start)
  ushort* w2b = (ushort*)(ws + (2u << 20));        // 2 MiB
  ushort* a1b = (ushort*)(ws + (4u << 20));        // 3 MiB: [eng;pos] bf16
  float*  xw1 = (float*)(ws + (7u << 20));         // 6 MiB: 1536x1024 f32
  ushort* hb  = (ushort*)(ws + (13u << 20));       // 64 MiB: 32768x1024 bf16

  // 1) fused casts to bf16 (w1|w2|eng|pos contiguous at ws base)
  cast_all_kernel<<<3584, 256, 0, stream>>>(w1, w2, eng, pos, w1b);

  // 2) GEMM1: xw1 = [engrams; pos] @ W1^T, +b1 folded into pos-rows
  gemm_bt<<<(A1_ROWS / 128) * (D_DIM / 128), 256, 0, stream>>>(a1b, w1b, xw1,
                                                               A1_ROWS, D_DIM, D_DIM,
                                                               b1, NE_ROWS);

  // 3) h = gelu(xw1_e + xw1_p) -> bf16   (b1 already folded)
  gelu_kernel<<<NROWS, 256, 0, stream>>>(xw1, hb);

  // 4) GEMM2: y(bf16) = h @ W2^T, interleaved into d_out rows; 2 blocks/CU
  gemm2_128<<<2048, 256, 0, stream>>>(hb, w2b, (ushort*)out);

  // 5) LayerNorm epilogue (exact fp32 residual recompute)
  ln_kernel<<<NROWS, 256, 0, stream>>>(eng, pos, b2, gamma, beta, out);
}

// Round 7
// 176.059 us; speedup vs baseline: 1.4223x; 1.0162x over previous
//
#include <hip/hip_runtime.h>
#include <hip/hip_bf16.h>
#include <math.h>

#define D_DIM 1024
#define NROWS 32768      // 4*16*512
#define NE_ROWS 1024     // 4*16*16 unique engram rows
#define A1_ROWS 1536     // engram rows + 512 pos rows
#define NT2 32           // GEMM2 K-steps of 32

typedef __attribute__((ext_vector_type(8))) short bf16x8;
typedef __attribute__((ext_vector_type(4))) float f32x4;

static __device__ __forceinline__ ushort f2bf(float f) {
  union { float f; unsigned u; } un; un.f = f;
  unsigned u = un.u;
  unsigned r = u + 0x7fffu + ((u >> 16) & 1u);
  return (ushort)(r >> 16);
}
static __device__ __forceinline__ float bf2f(ushort h) {
  union { unsigned u; float f; } un; un.u = ((unsigned)h) << 16;
  return un.f;
}
static __device__ __forceinline__ float gelu_exact(float v) {
  return 0.5f * v * (1.0f + erff(v * 0.70710678118654752f));
}

// ---- fused cast fp32 -> bf16 of w1|w2|eng|pos into contiguous ws region ----
__global__ void cast_all_kernel(const float* __restrict__ w1, const float* __restrict__ w2,
                                const float* __restrict__ eng, const float* __restrict__ pos,
                                ushort* __restrict__ dst) {
  int i = blockIdx.x * blockDim.x + threadIdx.x;   // float4 units, 0..917503
  float4 v;
  if (i < 262144) v = ((const float4*)w1)[i];
  else if (i < 524288) v = ((const float4*)w2)[i - 262144];
  else if (i < 786432) v = ((const float4*)eng)[i - 524288];
  else v = ((const float4*)pos)[i - 786432];
  ushort4 o;
  o.x = f2bf(v.x); o.y = f2bf(v.y); o.z = f2bf(v.z); o.w = f2bf(v.w);
  ((ushort4*)dst)[i] = o;
}

// ---- 128x128 bf16 MFMA GEMM + row-ranged bias (b1 folded into pos rows) ----
__global__ __launch_bounds__(256) void gemm_bt(const ushort* __restrict__ A,
                                               const ushort* __restrict__ B,
                                               float* __restrict__ C,
                                               int M, int N, int K,
                                               const float* __restrict__ bias,
                                               int biasRow0) {
  __shared__ ushort sA[128 * 64];
  __shared__ ushort sB[128 * 64];

  int nwg = gridDim.x;
  int bid = blockIdx.x;
  if ((nwg & 7) == 0) {
    int cpx = nwg >> 3;
    bid = (bid & 7) * cpx + (bid >> 3);
  }
  int ntn = N >> 7;
  int mt = bid / ntn, nt = bid % ntn;
  int brow = mt << 7, bcol = nt << 7;

  int tid = threadIdx.x;
  int wv = tid >> 6, lane = tid & 63;
  int wm = (wv >> 1) << 6, wn = (wv & 1) << 6;
  int lr = lane & 15, lk = lane >> 4;
  int srow = lane >> 3;
  int scolsw = (((lane & 7) ^ ((lane >> 3) & 7)) << 3);

  f32x4 acc[4][4];
#pragma unroll
  for (int m = 0; m < 4; ++m)
#pragma unroll
    for (int n = 0; n < 4; ++n) acc[m][n] = (f32x4){0.f, 0.f, 0.f, 0.f};

  for (int k0 = 0; k0 < K; k0 += 64) {
    __syncthreads();
#pragma unroll
    for (int j = 0; j < 4; ++j) {
      int c = (wv << 2) + j;
      int row = (c << 3) + srow;
      const ushort* gA = A + (brow + row) * K + k0 + scolsw;
      const ushort* gB = B + (bcol + row) * K + k0 + scolsw;
      __builtin_amdgcn_global_load_lds(
          (const __attribute__((address_space(1))) unsigned int*)gA,
          (__attribute__((address_space(3))) unsigned int*)&sA[c << 9], 16, 0, 0);
      __builtin_amdgcn_global_load_lds(
          (const __attribute__((address_space(1))) unsigned int*)gB,
          (__attribute__((address_space(3))) unsigned int*)&sB[c << 9], 16, 0, 0);
    }
    __syncthreads();
#pragma unroll
    for (int kk = 0; kk < 2; ++kk) {
      int rdoff = (((kk << 2) | lk) ^ (lr & 7)) << 3;
      bf16x8 af[4], bfr[4];
#pragma unroll
      for (int m = 0; m < 4; ++m)
        af[m] = *(const bf16x8*)&sA[(wm + (m << 4) + lr) * 64 + rdoff];
#pragma unroll
      for (int n = 0; n < 4; ++n)
        bfr[n] = *(const bf16x8*)&sB[(wn + (n << 4) + lr) * 64 + rdoff];
#pragma unroll
      for (int m = 0; m < 4; ++m)
#pragma unroll
        for (int n = 0; n < 4; ++n)
          acc[m][n] = __builtin_amdgcn_mfma_f32_16x16x32_bf16(af[m], bfr[n], acc[m][n], 0, 0, 0);
    }
  }

#pragma unroll
  for (int m = 0; m < 4; ++m)
#pragma unroll
    for (int n = 0; n < 4; ++n)
#pragma unroll
      for (int i = 0; i < 4; ++i) {
        int row = brow + wm + (m << 4) + (lk << 2) + i;
        int col = bcol + wn + (n << 4) + lr;
        float v = acc[m][n][i];
        if (row >= biasRow0) v += bias[col];
        C[(long)row * N + col] = v;
      }
}

// ---- h = gelu_exact(xw1_e[er] + xw1_p[w]) -> bf16 (b1 already in pos rows) ----
__global__ __launch_bounds__(256) void gelu_kernel(const float* __restrict__ xw1,
                                                   ushort* __restrict__ h) {
  int r = blockIdx.x;
  int t = threadIdx.x;
  int bn = r >> 9;
  int w = r & 511;
  int er = bn * 16 + (w >> 5);
  float4 e = ((const float4*)(xw1 + er * D_DIM))[t];
  float4 p = ((const float4*)(xw1 + (NE_ROWS + w) * D_DIM))[t];
  ushort4 o;
  o.x = f2bf(gelu_exact(e.x + p.x));
  o.y = f2bf(gelu_exact(e.y + p.y));
  o.z = f2bf(gelu_exact(e.z + p.z));
  o.w = f2bf(gelu_exact(e.w + p.w));
  ((ushort4*)(h + (long)r * D_DIM))[t] = o;
}

// ---- GEMM2: 128x128 tile, 4 waves, BK=32, 32 KiB LDS -> ~5 blocks/CU ----
// Y(bf16) = h @ W2^T, interleaved: ushort at Y + row*2048 + col.
// 2 LDS buffers [128r x 32k] each for A,B; depth-1 prefetch, counted vmcnt(4).
// Swizzle: phys 16B-slot s at row r holds logical s^((r>>1)&3).
__global__ __launch_bounds__(256, 4) void gemm2_128(const ushort* __restrict__ A,
                                                    const ushort* __restrict__ B,
                                                    ushort* __restrict__ Y) {
  __shared__ ushort sA[2][4096];
  __shared__ ushort sB[2][4096];
  const int K = 1024;

  // XCD map: all 8 N-tiles of an M-panel stay on one XCD (A L2-reuse)
  int bid = blockIdx.x;                // 2048 blocks
  int x = bid & 7, jj = bid >> 3;
  int mt = (x << 5) + (jj >> 3);       // 0..255
  int nt = jj & 7;                     // 0..7
  long brow = (long)mt << 7;
  int bcol = nt << 7;

  int tid = threadIdx.x;
  int wv = tid >> 6, l = tid & 63;
  int wr = wv >> 1, wc = wv & 1;       // 2x2 wave grid; wave tile 64x64
  int lr = l & 15, lk = l >> 4;

  // staging: instr j2 covers rows [j2*64, j2*64+64): row = j2*64 + wv*16 + (l>>2)
  // phys slot l&3; pre-swizzled logical slot (l&3)^((l>>3)&3)  [= (row>>1)&3]
  int srow0 = (wv << 4) + (l >> 2);
  int slog = (((l & 3) ^ ((l >> 3) & 3)) << 3);
  const ushort* aS = A + (brow + srow0) * (long)K + slog;
  const ushort* bS = B + (size_t)(bcol + srow0) * K + slog;

  // fragment read offsets (swizzled): row parity uses lr only (wr/wc/m strides ≡0 mod 4)
  int rdswz = (lk ^ ((lr >> 1) & 3)) << 3;
  int aO = (((wr << 6) + lr) << 5) + rdswz;   // + m<<9
  int bO = (((wc << 6) + lr) << 5) + rdswz;   // + n<<9

  f32x4 acc[4][4];
#pragma unroll
  for (int m = 0; m < 4; ++m)
#pragma unroll
    for (int n = 0; n < 4; ++n) acc[m][n] = (f32x4){0.f, 0.f, 0.f, 0.f};

#define STG(kt) do {                                                                 \
    int p_ = (kt) & 1; int ko_ = (kt) << 5;                                          \
    _Pragma("unroll")                                                                \
    for (int j2 = 0; j2 < 2; ++j2) {                                                 \
      __builtin_amdgcn_global_load_lds(                                              \
        (const __attribute__((address_space(1))) unsigned int*)(aS + ko_ + (long)(j2 << 6) * K), \
        (__attribute__((address_space(3))) unsigned int*)&sA[p_][(j2 << 11) + (wv << 9)], 16, 0, 0); \
      __builtin_amdgcn_global_load_lds(                                              \
        (const __attribute__((address_space(1))) unsigned int*)(bS + ko_ + (long)(j2 << 6) * K), \
        (__attribute__((address_space(3))) unsigned int*)&sB[p_][(j2 << 11) + (wv << 9)], 16, 0, 0); \
    } } while (0)

#define BAR asm volatile("s_barrier" ::: "memory")

  // prologue: tiles 0,1 in flight; certify tile 0 (counted: 8 outstanding -> 4)
  STG(0); STG(1);
  asm volatile("s_waitcnt vmcnt(4)" ::: "memory");
  BAR;

  for (int t = 0; t < NT2; ++t) {
    int p = t & 1;
    bf16x8 af[4], bf[4];
#pragma unroll
    for (int n = 0; n < 4; ++n) bf[n] = *(const bf16x8*)&sB[p][bO + (n << 9)];
#pragma unroll
    for (int m = 0; m < 4; ++m) af[m] = *(const bf16x8*)&sA[p][aO + (m << 9)];
    __builtin_amdgcn_s_setprio(1);
#pragma unroll
    for (int m = 0; m < 4; ++m)
#pragma unroll
      for (int n = 0; n < 4; ++n)
        acc[m][n] = __builtin_amdgcn_mfma_f32_16x16x32_bf16(af[m], bf[n], acc[m][n], 0, 0, 0);
    __builtin_amdgcn_s_setprio(0);
    if (t == NT2 - 1) break;
    BAR;   // all waves done reading buf[t&1] (MFMA consumed the ds_reads)
    if (t + 2 < NT2) {
      STG(t + 2);                                        // overwrites buf[t&1]
      asm volatile("s_waitcnt vmcnt(4)" ::: "memory");   // certify buf[(t+1)&1]
    } else {
      asm volatile("s_waitcnt vmcnt(0)" ::: "memory");   // tail certify
    }
    BAR;   // buf[(t+1)&1] visible to all
  }
#undef STG
#undef BAR

  // epilogue: bf16 y into interleaved out rows (first 1024 ushorts of 4KB row)
#pragma unroll
  for (int m = 0; m < 4; ++m)
#pragma unroll
    for (int n = 0; n < 4; ++n) {
      int col = bcol + (wc << 6) + (n << 4) + lr;
#pragma unroll
      for (int i = 0; i < 4; ++i) {
        long row = brow + (wr << 6) + (m << 4) + (lk << 2) + i;
        Y[(row << 11) + col] = f2bf(acc[m][n][i]);
      }
    }
}

// ---- out = LayerNorm((eng+pos) + y + b2); y read bf16-interleaved from out ----
__global__ __launch_bounds__(256) void ln_kernel(const float* __restrict__ eng,
                                                 const float* __restrict__ pos,
                                                 const float* __restrict__ b2,
                                                 const float* __restrict__ gamma,
                                                 const float* __restrict__ beta,
                                                 float* __restrict__ out) {
  __shared__ float red[8];
  int r = blockIdx.x;
  int t = threadIdx.x;
  int bn = r >> 9, w = r & 511;
  int er = bn * 16 + (w >> 5);
  float4 xe = ((const float4*)(eng + er * D_DIM))[t];
  float4 xp = ((const float4*)(pos + w * D_DIM))[t];
  ushort4 yv = ((const ushort4*)((const ushort*)out + ((size_t)r << 11)))[t];
  float4 bb = ((const float4*)b2)[t];
  float v0 = xe.x + xp.x + bf2f(yv.x) + bb.x;
  float v1 = xe.y + xp.y + bf2f(yv.y) + bb.y;
  float v2 = xe.z + xp.z + bf2f(yv.z) + bb.z;
  float v3 = xe.w + xp.w + bf2f(yv.w) + bb.w;
  float s  = v0 + v1 + v2 + v3;
  float sq = v0 * v0 + v1 * v1 + v2 * v2 + v3 * v3;
  int lane = t & 63, wv = t >> 6;
#pragma unroll
  for (int off = 32; off > 0; off >>= 1) {
    s  += __shfl_down(s, off);
    sq += __shfl_down(sq, off);
  }
  if (lane == 0) { red[wv] = s; red[4 + wv] = sq; }
  __syncthreads();
  float S  = red[0] + red[1] + red[2] + red[3];
  float SQ = red[4] + red[5] + red[6] + red[7];
  float mu = S * (1.0f / 1024.0f);
  float var = SQ * (1.0f / 1024.0f) - mu * mu;
  float rs = rsqrtf(var + 1e-5f);
  float4 g = ((const float4*)gamma)[t];
  float4 bt = ((const float4*)beta)[t];
  float4 o;
  o.x = (v0 - mu) * rs * g.x + bt.x;
  o.y = (v1 - mu) * rs * g.y + bt.y;
  o.z = (v2 - mu) * rs * g.z + bt.z;
  o.w = (v3 - mu) * rs * g.w + bt.w;
  ((float4*)(out + ((size_t)r << 10)))[t] = o;
}

extern "C" void kernel_launch(void* const* d_in, const int* in_sizes, int n_in,
                              void* d_out, int out_size, void* d_ws, size_t ws_size,
                              hipStream_t stream) {
  const float* eng   = (const float*)d_in[0];
  const float* pos   = (const float*)d_in[1];
  const float* w1    = (const float*)d_in[2];
  const float* b1    = (const float*)d_in[3];
  const float* w2    = (const float*)d_in[4];
  const float* b2    = (const float*)d_in[5];
  const float* gamma = (const float*)d_in[6];
  const float* beta  = (const float*)d_in[7];
  float* out = (float*)d_out;

  char* ws = (char*)d_ws;
  ushort* w1b = (ushort*)(ws);                     // 2 MiB  (cast block start)
  ushort* w2b = (ushort*)(ws + (2u << 20));        // 2 MiB
  ushort* a1b = (ushort*)(ws + (4u << 20));        // 3 MiB: [eng;pos] bf16
  float*  xw1 = (float*)(ws + (7u << 20));         // 6 MiB: 1536x1024 f32
  ushort* hb  = (ushort*)(ws + (13u << 20));       // 64 MiB: 32768x1024 bf16

  // 1) fused casts to bf16 (w1|w2|eng|pos contiguous at ws base)
  cast_all_kernel<<<3584, 256, 0, stream>>>(w1, w2, eng, pos, w1b);

  // 2) GEMM1: xw1 = [engrams; pos] @ W1^T, +b1 folded into pos-rows
  gemm_bt<<<(A1_ROWS / 128) * (D_DIM / 128), 256, 0, stream>>>(a1b, w1b, xw1,
                                                               A1_ROWS, D_DIM, D_DIM,
                                                               b1, NE_ROWS);

  // 3) h = gelu(xw1_e + xw1_p) -> bf16   (b1 already folded)
  gelu_kernel<<<NROWS, 256, 0, stream>>>(xw1, hb);

  // 4) GEMM2: y(bf16) = h @ W2^T, interleaved into d_out rows; ~5 blocks/CU
  gemm2_128<<<2048, 256, 0, stream>>>(hb, w2b, (ushort*)out);

  // 5) LayerNorm epilogue (exact fp32 residual recompute)
  ln_kernel<<<NROWS, 256, 0, stream>>>(eng, pos, b2, gamma, beta, out);
}